// Round 18
// baseline (1159.112 us; speedup 1.0000x reference)
//
#include <hip/hip_runtime.h>
#include <math.h>

// Problem constants
#define Vv 8000
#define Ee 256
#define Hh 256
#define Tt 4
#define Bb 64
#define Ss 512

#define EPROJ_PER_DIR (Vv * 1024)   // 8,192,000 floats per direction
#define WMAT_PER_DIR  (Ee * 1024)   // 262,144 floats per direction

// R18 int8 weight image (per dir = 65536 u32 = 256KB), 1024-thread k-split:
//   thread t: kh = t>>9 (k-half), tt = t&511 (unit-pair thread).
//   Each thread covers 16 k-words: kw = 32*kh + [0..15]; LDS-static slots
//   0..NSTAT-1 (kw offset 2*slot+(j>>1)), streamed slots (offset 2*NSTAT+...).
//   u32 at (sec, slot, t, j):
//     kw = 32*(t>>9) + (sec? 2*NSTAT:0) + 2*slot + (j>>1), rr = j&1
//     u = (t&511)>>1, gs = ((t&511)&1)*2 + rr, row = gs*256 + u
//   Thread t consumes uint4 (slot*1024+t) -> lane-linear, conflict-free.
#define NSTAT 4
#define NSTRM 12
#define STAT_U32 (NSTAT * 1024 * 4)   // 16384

#if defined(__has_builtin)
# if __has_builtin(__builtin_amdgcn_sdot4)
#  define HAS_SDOT4 1
# endif
# if __has_builtin(__builtin_amdgcn_exp2f) && __has_builtin(__builtin_amdgcn_rcpf)
#  define HAS_FASTTRANS 1
# endif
#endif

__device__ __forceinline__ float sigm(float x) { return 1.f / (1.f + expf(-x)); }

__device__ __forceinline__ float sigm_f(float x) {
#ifdef HAS_FASTTRANS
    const float e = __builtin_amdgcn_exp2f(-1.44269504f * x);
    return __builtin_amdgcn_rcpf(1.f + e);
#else
    return 1.f / (1.f + expf(-x));
#endif
}
__device__ __forceinline__ float tanh_f(float x) {
#ifdef HAS_FASTTRANS
    const float e = __builtin_amdgcn_exp2f(-2.88539008f * x);
    return 2.f * __builtin_amdgcn_rcpf(1.f + e) - 1.f;
#else
    return tanhf(x);
#endif
}

__device__ __forceinline__ int dot4i8(unsigned a, unsigned b, int c) {
#ifdef HAS_SDOT4
    return __builtin_amdgcn_sdot4((int)a, (int)b, c, false);
#else
    int s = c;
    #pragma unroll
    for (int i = 0; i < 4; ++i) {
        const int xa = ((int)(a << (24 - 8 * i))) >> 24;
        const int xb = ((int)(b << (24 - 8 * i))) >> 24;
        s += xa * xb;
    }
    return s;
#endif
}

// ---------------------------------------------------------------------------
// prep1: WihP (GEMM B-matrix, j' = u*4+g <-> gate-row g*256+u), bP, WlinQ.
// ---------------------------------------------------------------------------
__global__ void prep1_kernel(const float* __restrict__ Wih_f, const float* __restrict__ b_f,
                             const float* __restrict__ Wih_b, const float* __restrict__ b_b,
                             const float* __restrict__ Wlin,
                             float* __restrict__ WihP, float* __restrict__ bP,
                             float* __restrict__ WlinQ)
{
    int tid = blockIdx.x * blockDim.x + threadIdx.x;   // [0, 2*262144)
    int dir = tid >> 18;
    int r   = tid & 262143;
    int k   = r >> 10;        // 0..255
    int jp  = r & 1023;       // j'
    int u   = jp >> 2;
    int g   = jp & 3;
    int row = g * 256 + u;
    const float* Wih = dir ? Wih_b : Wih_f;
    const float* bv  = dir ? b_b   : b_f;
    WihP[dir * WMAT_PER_DIR + k * 1024 + jp] = Wih[row * 256 + k];
    if (r < 1024) {
        bP[dir * 1024 + jp] = bv[row];
        int uu = r >> 2, tt = r & 3;
        WlinQ[(dir * 256 + uu) * 4 + tt] = Wlin[tt * (2 * Hh) + dir * 256 + uu];
    }
}

// ---------------------------------------------------------------------------
// scale_kernel: per gate-row absmax/127. 512 blocks x 256 thr; wave = one row.
// ---------------------------------------------------------------------------
__global__ __launch_bounds__(256) void scale_kernel(const float* __restrict__ Whh_f,
                                                    const float* __restrict__ Whh_b,
                                                    float* __restrict__ scales)
{
    const int gw = blockIdx.x * 4 + (threadIdx.x >> 6);   // 0..2047
    const int lane = threadIdx.x & 63;
    const int dir = gw >> 10;
    const int row = gw & 1023;
    const float* W = dir ? Whh_b : Whh_f;
    const float* src = W + (size_t)row * 256 + lane * 4;
    float m = fmaxf(fmaxf(fabsf(src[0]), fabsf(src[1])),
                    fmaxf(fabsf(src[2]), fabsf(src[3])));
    #pragma unroll
    for (int off = 32; off > 0; off >>= 1) m = fmaxf(m, __shfl_down(m, off));
    if (lane == 0) scales[gw] = fmaxf(m, 1e-12f) / 127.f;
}

// ---------------------------------------------------------------------------
// quant_kernel: build the permuted int8 image W8 (R18 1024-thread k-split).
// ---------------------------------------------------------------------------
__global__ __launch_bounds__(256) void quant_kernel(const float* __restrict__ Whh_f,
                                                    const float* __restrict__ Whh_b,
                                                    const float* __restrict__ scales,
                                                    unsigned int* __restrict__ W8)
{
    const int idx = blockIdx.x * 256 + threadIdx.x;   // 0..131071
    const int dir = idx >> 16;
    const int rem = idx & 65535;
    int slot, t, j, kwoff;
    if (rem < STAT_U32) {
        slot = rem >> 12; const int r2 = rem & 4095; t = r2 >> 2; j = r2 & 3;
        kwoff = 2 * slot + (j >> 1);
    } else {
        const int q2 = rem - STAT_U32;
        slot = q2 >> 12; const int r2 = q2 & 4095; t = r2 >> 2; j = r2 & 3;
        kwoff = 2 * NSTAT + 2 * slot + (j >> 1);
    }
    const int kw = 32 * (t >> 9) + kwoff;
    const int rr = j & 1;
    const int tt = t & 511;
    const int u  = tt >> 1;
    const int gs = (tt & 1) * 2 + rr;
    const int row = gs * 256 + u;
    const float* W = dir ? Whh_b : Whh_f;
    const float sc = scales[dir * 1024 + row];
    const float inv = 1.f / sc;
    unsigned int v = 0;
    #pragma unroll
    for (int i = 0; i < 4; ++i) {
        const float w = W[(size_t)row * 256 + kw * 4 + i];
        int q = (int)rintf(w * inv);
        q = q > 127 ? 127 : (q < -127 ? -127 : q);
        v |= ((unsigned int)(unsigned char)(signed char)q) << (8 * i);
    }
    W8[idx] = v;
}

// ---------------------------------------------------------------------------
// wl8_kernel: quantize emission weights per (dir, tag). 1 block x 512 thr.
// ---------------------------------------------------------------------------
__global__ __launch_bounds__(512) void wl8_kernel(const float* __restrict__ Wlin,
                                                  unsigned int* __restrict__ wl8T,
                                                  float* __restrict__ scfac)
{
    const int w = threadIdx.x >> 6;      // 0..7
    const int lane = threadIdx.x & 63;
    const int dir = w >> 2, t = w & 3;
    const float4 v = *(const float4*)(Wlin + t * (2 * Hh) + dir * 256 + lane * 4);
    float m = fmaxf(fmaxf(fabsf(v.x), fabsf(v.y)), fmaxf(fabsf(v.z), fabsf(v.w)));
    #pragma unroll
    for (int off = 32; off > 0; off >>= 1) m = fmaxf(m, __shfl_down(m, off));
    const float mall = __builtin_amdgcn_readfirstlane(m);
    const float sc = fmaxf(mall, 1e-12f) / 127.f;
    const float inv = 1.f / sc;
    const float vv[4] = {v.x, v.y, v.z, v.w};
    unsigned int pk = 0;
    #pragma unroll
    for (int i = 0; i < 4; ++i) {
        int q = (int)rintf(vv[i] * inv);
        q = q > 127 ? 127 : (q < -127 ? -127 : q);
        pk |= ((unsigned int)(unsigned char)(signed char)q) << (8 * i);
    }
    wl8T[w * 64 + lane] = pk;
    if (lane == 0) scfac[w] = sc / 127.f;
}

// ---------------------------------------------------------------------------
// embproj GEMM: embproj[dir][v][j'] = sum_e emb[v][e]*WihP[dir][e][j'] + bP[dir][j']
// ---------------------------------------------------------------------------
#define BM 64
#define BN 128
#define BK 16
__global__ __launch_bounds__(256) void embproj_gemm(const float* __restrict__ emb,
                                                    const float* __restrict__ WihP,
                                                    const float* __restrict__ bP,
                                                    float* __restrict__ embproj)
{
    int dir = blockIdx.z;
    const float* Bmat = WihP + dir * WMAT_PER_DIR;
    float* C = embproj + (size_t)dir * EPROJ_PER_DIR;
    int m0 = blockIdx.x * BM;
    int n0 = blockIdx.y * BN;

    __shared__ float As[BK][BM];
    __shared__ float Bs[BK][BN];

    int t = threadIdx.x;
    int tm = (t & 15) * 4;
    int tn = (t >> 4) * 8;
    float acc[4][8];
    #pragma unroll
    for (int i = 0; i < 4; ++i)
        #pragma unroll
        for (int j = 0; j < 8; ++j) acc[i][j] = 0.f;

    for (int k0 = 0; k0 < Ee; k0 += BK) {
        {   // A tile 64x16
            int row = t >> 2, seg = t & 3;
            float4 a4 = *(const float4*)(&emb[(size_t)(m0 + row) * Ee + k0 + seg * 4]);
            As[seg * 4 + 0][row] = a4.x;
            As[seg * 4 + 1][row] = a4.y;
            As[seg * 4 + 2][row] = a4.z;
            As[seg * 4 + 3][row] = a4.w;
        }
        {   // B tile 16x128
            int kk = t >> 4, nn = (t & 15) * 8;
            float4 b0 = *(const float4*)(&Bmat[(size_t)(k0 + kk) * 1024 + n0 + nn]);
            float4 b1 = *(const float4*)(&Bmat[(size_t)(k0 + kk) * 1024 + n0 + nn + 4]);
            *(float4*)&Bs[kk][nn]     = b0;
            *(float4*)&Bs[kk][nn + 4] = b1;
        }
        __syncthreads();
        #pragma unroll
        for (int k = 0; k < BK; ++k) {
            float4 a  = *(const float4*)&As[k][tm];
            float4 b0 = *(const float4*)&Bs[k][tn];
            float4 b1 = *(const float4*)&Bs[k][tn + 4];
            float av[4] = {a.x, a.y, a.z, a.w};
            float bv[8] = {b0.x, b0.y, b0.z, b0.w, b1.x, b1.y, b1.z, b1.w};
            #pragma unroll
            for (int i = 0; i < 4; ++i)
                #pragma unroll
                for (int j = 0; j < 8; ++j)
                    acc[i][j] += av[i] * bv[j];
        }
        __syncthreads();
    }
    #pragma unroll
    for (int i = 0; i < 4; ++i) {
        int m = m0 + tm + i;
        #pragma unroll
        for (int j = 0; j < 8; j += 4) {
            float4 o;
            o.x = acc[i][j + 0] + bP[dir * 1024 + n0 + tn + j + 0];
            o.y = acc[i][j + 1] + bP[dir * 1024 + n0 + tn + j + 1];
            o.z = acc[i][j + 2] + bP[dir * 1024 + n0 + tn + j + 2];
            o.w = acc[i][j + 3] + bP[dir * 1024 + n0 + tn + j + 3];
            *(float4*)&C[(size_t)m * 1024 + n0 + tn + j] = o;
        }
    }
}

// ---------------------------------------------------------------------------
// R18 LSTM: k-split 1024-thread WG (16 waves = 4/SIMD, 2x the latency hiding;
// R17 analysis: VALU issue was only ~1/3 of step time at 2 waves/SIMD, the
// rest exposed L2/RAW/barrier stalls). Thread (kh, tt): kh = k-half (32 kw),
// tt = unit-pair as before. kh=1 posts exact int partials via LDS; kh=0 sums,
// activates, publishes h. Everything else identical to R17 (sync-free,
// fast transcendentals, emission on waves 4-7, ep pipelined).
// ---------------------------------------------------------------------------
__global__ __attribute__((amdgpu_flat_work_group_size(1024, 1024)))
__attribute__((amdgpu_waves_per_eu(4, 4))) void lstm_stream_kernel(
    const int* __restrict__ sentence,
    const float* __restrict__ embproj,
    const unsigned int* __restrict__ W8,
    const float* __restrict__ scales,
    const unsigned int* __restrict__ wl8T,
    const float* __restrict__ scfac,
    float* __restrict__ emisP)
{
    extern __shared__ char smem[];
    uint4*        SWl  = (uint4*)smem;                        // NSTAT*1024 uint4 = 64KB
    unsigned int* h8   = (unsigned int*)(smem + STAT_U32*4);  // [2][64] u32
    int2*         part = (int2*)(smem + STAT_U32*4 + 512);    // [512] int2

    const int bx  = blockIdx.x;
    const int dir = bx >> 6;
    const int b   = bx & 63;
    const int t   = threadIdx.x;
    const int lane = t & 63, wv = t >> 6;
    const int kh  = t >> 9;             // k-half
    const int tt  = t & 511;
    const int u    = tt >> 1;           // pair-lane unit
    const int gs0  = (tt & 1) * 2;      // 0: rows i,f | 2: rows g,o
    const bool ev  = !(tt & 1);
    const int kwb  = 32 * kh;           // this thread's k-word base

    const unsigned int* Wd   = W8 + (size_t)dir * 65536;
    const unsigned int* Wstr = Wd + STAT_U32;

    // stage static weight section into LDS (coalesced)
    #pragma unroll
    for (int i = 0; i < NSTAT; ++i)
        SWl[i * 1024 + t] = *(const uint4*)(Wd + (size_t)(i * 1024 + t) * 4);
    if (t < 128) h8[t] = 0u;   // h(-1) = 0, both parity slots

    const float sc0 = scales[dir * 1024 + (gs0 + 0) * 256 + u] * (1.f / 127.f);
    const float sc1 = scales[dir * 1024 + (gs0 + 1) * 256 + u] * (1.f / 127.f);
    const float* EP = embproj + (size_t)dir * EPROJ_PER_DIR;
    const int* sent = sentence + (size_t)b * Ss;
    float c = 0.f;

    // emission state: waves 4..7 (kh=0), one tag each
    unsigned int wlq = 0;
    float efac = 0.f;
    const int etag = wv - 4;
    if (wv >= 4 && wv < 8) {
        wlq  = wl8T[(dir * 4 + etag) * 64 + lane];
        efac = scfac[dir * 4 + etag];
    }

    // ep software pipeline: preload step 0 (kh=0 only consumes it)
    float2 ep_cur = make_float2(0.f, 0.f);
    if (kh == 0) {
        const int pos0 = dir ? (Ss - 1) : 0;
        ep_cur = *(const float2*)(EP + (size_t)sent[pos0] * 1024 + u * 4 + gs0);
    }

    __syncthreads();

    for (int s = 0; s < Ss; ++s) {
        // issue next step's ep load early
        float2 ep_nxt = make_float2(0.f, 0.f);
        if (kh == 0 && s + 1 < Ss) {
            const int pn = dir ? (Ss - 2 - s) : (s + 1);
            ep_nxt = *(const float2*)(EP + (size_t)sent[pn] * 1024 + u * 4 + gs0);
        }

        const int rp = (s + 1) & 1;        // slot holding h(s-1)
        const int wp = s & 1;              // slot to write h(s)
        const int v_h = (int)h8[rp * 64 + lane];

        // streamed weight slots (L2-resident)
        uint4 sb[NSTRM];
        #pragma unroll
        for (int i = 0; i < NSTRM; ++i)
            sb[i] = *(const uint4*)(Wstr + (size_t)(i * 1024 + t) * 4);

        // emission of h(s-1): waves 4-7, one tag each
        if (wv >= 4 && wv < 8 && s > 0) {
            int e = dot4i8(wlq, (unsigned)v_h, 0);
            #pragma unroll
            for (int off = 32; off > 0; off >>= 1) e += __shfl_down(e, off);
            if (lane == 0) {
                const int pp = dir ? (Ss - s) : (s - 1);
                emisP[(((size_t)dir * Ss + pp) * Bb + b) * 4 + etag] = (float)e * efac;
            }
        }

        // gate dots over this thread's 16 k-words; 4 chains per output
        int a0c[4] = {0, 0, 0, 0};
        int a1c[4] = {0, 0, 0, 0};
        #pragma unroll
        for (int i = 0; i < NSTAT; ++i) {
            const uint4 w = SWl[i * 1024 + t];
            const unsigned h0 = (unsigned)__builtin_amdgcn_readlane(v_h, kwb + 2 * i);
            const unsigned h1 = (unsigned)__builtin_amdgcn_readlane(v_h, kwb + 2 * i + 1);
            const int q = i & 3;
            a0c[q] = dot4i8(w.x, h0, a0c[q]); a1c[q] = dot4i8(w.y, h0, a1c[q]);
            a0c[q] = dot4i8(w.z, h1, a0c[q]); a1c[q] = dot4i8(w.w, h1, a1c[q]);
        }
        #pragma unroll
        for (int i = 0; i < NSTRM; ++i) {
            const uint4 w = sb[i];
            const unsigned h0 = (unsigned)__builtin_amdgcn_readlane(v_h, kwb + 2 * NSTAT + 2 * i);
            const unsigned h1 = (unsigned)__builtin_amdgcn_readlane(v_h, kwb + 2 * NSTAT + 2 * i + 1);
            const int q = i & 3;
            a0c[q] = dot4i8(w.x, h0, a0c[q]); a1c[q] = dot4i8(w.y, h0, a1c[q]);
            a0c[q] = dot4i8(w.z, h1, a0c[q]); a1c[q] = dot4i8(w.w, h1, a1c[q]);
        }
        const int a0 = (a0c[0] + a0c[1]) + (a0c[2] + a0c[3]);
        const int a1 = (a1c[0] + a1c[1]) + (a1c[2] + a1c[3]);

        if (kh == 1) part[tt] = make_int2(a0, a1);
        __syncthreads();   // B1: partials posted; h8 reads of this step done

        if (kh == 0) {
            const int2 p = part[tt];
            const float g0 = (float)(a0 + p.x) * sc0 + ep_cur.x;   // ev: i | odd: g
            const float g1 = (float)(a1 + p.y) * sc1 + ep_cur.y;   // ev: f | odd: o
            const float pg0 = __shfl_xor(g0, 1);
            const float pg1 = __shfl_xor(g1, 1);
            if (ev) {
                c = sigm_f(g1) * c + sigm_f(g0) * tanh_f(pg0);
                const float h = sigm_f(pg1) * tanh_f(c);
                ((char*)h8)[wp * 256 + u] = (char)(int)rintf(h * 127.f);   // |h|<1
            }
        }
        ep_cur = ep_nxt;
        __syncthreads();   // B2: h(s) visible for step s+1
    }

    // epilogue: emission for h(Ss-1)
    if (wv >= 4 && wv < 8) {
        const int v_h = (int)h8[((Ss - 1) & 1) * 64 + lane];
        int e = dot4i8(wlq, (unsigned)v_h, 0);
        #pragma unroll
        for (int off = 32; off > 0; off >>= 1) e += __shfl_down(e, off);
        if (lane == 0) {
            const int pp = dir ? 0 : (Ss - 1);
            emisP[(((size_t)dir * Ss + pp) * Bb + b) * 4 + etag] = (float)e * efac;
        }
    }
}

// ---------------------------------------------------------------------------
// Fused CRF + Viterbi tail. grid 8 x 64 threads. emis = emisP[0] + emisP[1].
// ---------------------------------------------------------------------------
#define EM2(S_, B_, J_) (emisA[(((size_t)(S_)) * Bb + (B_)) * 4 + (J_)] + \
                         emisB[(((size_t)(S_)) * Bb + (B_)) * 4 + (J_)])

__global__ __launch_bounds__(64) void tail_kernel(
    const float* __restrict__ emisA, const float* __restrict__ emisB,
    const float* __restrict__ blin, const float* __restrict__ start_t,
    const float* __restrict__ end_t, const float* __restrict__ trans,
    const int* __restrict__ tags, float* __restrict__ out_tags,
    float* __restrict__ out_loss)
{
    const int blk = blockIdx.x;
    const int t = threadIdx.x;
    const int b_loc = t >> 2, j = t & 3;
    const int base = t & ~3;

    if (blk < 4) {
        __shared__ unsigned char bp_sh[16][513][4];
        __shared__ unsigned char tag_sh[16][520];
        const int b = blk * 16 + b_loc;
        const float trj0 = trans[0*4+j], trj1 = trans[1*4+j],
                    trj2 = trans[2*4+j], trj3 = trans[3*4+j];
        const float blj = blin[j];
        float score = start_t[j] + EM2(0, b, j) + blj;
        for (int s = 1; s < Ss; ++s) {
            const float e = EM2(s, b, j) + blj;
            const float s0 = __shfl(score, base+0), s1 = __shfl(score, base+1),
                        s2 = __shfl(score, base+2), s3 = __shfl(score, base+3);
            float best = s0 + trj0; int bi = 0;
            float v = s1 + trj1; if (v > best) { best = v; bi = 1; }
            v = s2 + trj2; if (v > best) { best = v; bi = 2; }
            v = s3 + trj3; if (v > best) { best = v; bi = 3; }
            score = best + e;
            bp_sh[b_loc][s][j] = (unsigned char)bi;
        }
        const float fv = score + end_t[j];
        const float f0 = __shfl(fv, base+0), f1 = __shfl(fv, base+1),
                    f2 = __shfl(fv, base+2), f3 = __shfl(fv, base+3);
        __syncthreads();
        if (j == 0) {   // backtrack (first-occurrence argmax, like jnp)
            float best = f0; int tag = 0;
            if (f1 > best) { best = f1; tag = 1; }
            if (f2 > best) { best = f2; tag = 2; }
            if (f3 > best) { best = f3; tag = 3; }
            tag_sh[b_loc][Ss-1] = (unsigned char)tag;
            for (int s = Ss - 1; s >= 1; --s) {
                tag = bp_sh[b_loc][s][tag];
                tag_sh[b_loc][s-1] = (unsigned char)tag;
            }
        }
        __syncthreads();
        for (int idx = t; idx < 16 * Ss; idx += 64) {
            const int bl = idx >> 9, s = idx & (Ss - 1);
            out_tags[(size_t)(blk*16 + bl) * Ss + s] = (float)tag_sh[bl][s];
        }
    } else {
        const int b = (blk - 4) * 16 + b_loc;
        const float trj0 = trans[0*4+j], trj1 = trans[1*4+j],
                    trj2 = trans[2*4+j], trj3 = trans[3*4+j];
        const float blj = blin[j];
        float alpha = start_t[j] + EM2(0, b, j) + blj;
        for (int s = 1; s < Ss; ++s) {
            const float e = EM2(s, b, j) + blj;
            const float a0 = __shfl(alpha, base+0), a1 = __shfl(alpha, base+1),
                        a2 = __shfl(alpha, base+2), a3 = __shfl(alpha, base+3);
            const float x0 = a0 + trj0, x1 = a1 + trj1, x2 = a2 + trj2, x3 = a3 + trj3;
            const float m = fmaxf(fmaxf(x0, x1), fmaxf(x2, x3));
            alpha = m + logf(expf(x0-m) + expf(x1-m) + expf(x2-m) + expf(x3-m)) + e;
        }
        const float dv = alpha + end_t[j];
        const float d0 = __shfl(dv, base+0), d1 = __shfl(dv, base+1),
                    d2 = __shfl(dv, base+2), d3 = __shfl(dv, base+3);
        const float dm = fmaxf(fmaxf(d0, d1), fmaxf(d2, d3));
        const float denom = dm + logf(expf(d0-dm) + expf(d1-dm) + expf(d2-dm) + expf(d3-dm));

        const int lo = j * 128, hi = lo + 128;
        float num = 0.f;
        int tprev = (lo > 0) ? tags[(size_t)b*Ss + lo - 1] : 0;
        if (j == 0) num += start_t[tags[(size_t)b*Ss]];
        if (j == 3) num += end_t[tags[(size_t)b*Ss + Ss - 1]];
        for (int s = lo; s < hi; ++s) {
            const int tg = tags[(size_t)b*Ss + s];
            num += EM2(s, b, tg) + blin[tg];
            if (s > 0) num += trans[tprev*4 + tg];
            tprev = tg;
        }
        num += __shfl_xor(num, 1);
        num += __shfl_xor(num, 2);
        float lb = (j == 0) ? (denom - num) : 0.f;
        #pragma unroll
        for (int off = 32; off > 0; off >>= 1) lb += __shfl_down(lb, off);
        if (t == 0) atomicAdd(out_loss, lb);
    }
}

// ---------------------------------------------------------------------------
extern "C" void kernel_launch(void* const* d_in, const int* in_sizes, int n_in,
                              void* d_out, int out_size, void* d_ws, size_t ws_size,
                              hipStream_t stream)
{
    const int*   sentence = (const int*)d_in[0];
    const int*   tags     = (const int*)d_in[1];
    const float* emb      = (const float*)d_in[3];
    const float* Wih_f    = (const float*)d_in[4];
    const float* Whh_f    = (const float*)d_in[5];
    const float* b_f      = (const float*)d_in[6];
    const float* Wih_b    = (const float*)d_in[7];
    const float* Whh_b    = (const float*)d_in[8];
    const float* b_b      = (const float*)d_in[9];
    const float* Wlin     = (const float*)d_in[10];
    const float* blin     = (const float*)d_in[11];
    const float* start_t  = (const float*)d_in[12];
    const float* end_t    = (const float*)d_in[13];
    const float* trans    = (const float*)d_in[14];

    // workspace layout (floats)
    float*        embproj = (float*)d_ws;                      // 16,384,000
    float*        WihP    = embproj + 2 * EPROJ_PER_DIR;       // 524,288
    float*        bP      = WihP + 2 * WMAT_PER_DIR;           // 2048
    float*        WlinQ   = bP + 2048;                         // 2048
    float*        scales  = WlinQ + 2048;                      // 2048
    unsigned int* W8      = (unsigned int*)(scales + 2048);    // 131,072 u32
    unsigned int* wl8T    = W8 + 131072;                       // 512 u32
    float*        scfac   = (float*)(wl8T + 512);              // 8
    float*        emisP   = scfac + 56;                        // 2*512*64*4 (16B aligned)
    float*        emisA   = emisP;
    float*        emisB   = emisP + Ss * Bb * 4;

    prep1_kernel<<<2048, 256, 0, stream>>>(Wih_f, b_f, Wih_b, b_b, Wlin,
                                           WihP, bP, WlinQ);
    scale_kernel<<<512, 256, 0, stream>>>(Whh_f, Whh_b, scales);
    quant_kernel<<<512, 256, 0, stream>>>(Whh_f, Whh_b, scales, W8);
    wl8_kernel<<<1, 512, 0, stream>>>(Wlin, wl8T, scfac);

    dim3 gg(Vv / BM, 1024 / BN, 2);
    embproj_gemm<<<gg, 256, 0, stream>>>(emb, WihP, bP, embproj);

    lstm_stream_kernel<<<128, 1024, STAT_U32 * 4 + 512 + 4096, stream>>>(
        sentence, embproj, W8, scales, wl8T, scfac, emisP);

    float* out = (float*)d_out;
    float* out_loss = out + Bb * Ss;
    hipMemsetAsync(out_loss, 0, sizeof(float), stream);
    tail_kernel<<<8, 64, 0, stream>>>(emisA, emisB, blin, start_t, end_t, trans,
                                      tags, out, out_loss);
}

// Round 19
// 900.471 us; speedup vs baseline: 1.2872x; 1.2872x over previous
//
#include <hip/hip_runtime.h>
#include <math.h>

// Problem constants
#define Vv 8000
#define Ee 256
#define Hh 256
#define Tt 4
#define Bb 64
#define Ss 512

#define EPROJ_PER_DIR (Vv * 1024)   // 8,192,000 floats per direction
#define WMAT_PER_DIR  (Ee * 1024)   // 262,144 floats per direction

// int8 weight image geometry (per dir = 65536 u32 = 256KB):
//   64 k-words (kw) of 4 k each. LDS-static kw 0..2*NSTAT-1, L2-streamed
//   kw 2*NSTAT..63. u32 at (sec, slot, t, j):
//     kw = (sec? 2*NSTAT:0) + 2*slot + (j>>1), rr = j&1
//     PAIR-LANE mapping: u = t>>1, gs = (t&1)*2 + rr
//     row_orig = gs*256 + u   [gate-major, as input Whh]
//   Thread t consumes uint4 (slot*512+t) -> lane-linear, coalesced/conflict-free.
#define NSTAT 8
#define NSTRM 24
#define STAT_U32 (NSTAT * 512 * 4)   // 16384

#if defined(__has_builtin)
# if __has_builtin(__builtin_amdgcn_sdot4)
#  define HAS_SDOT4 1
# endif
# if __has_builtin(__builtin_amdgcn_exp2f) && __has_builtin(__builtin_amdgcn_rcpf)
#  define HAS_FASTTRANS 1
# endif
#endif

__device__ __forceinline__ float sigm(float x) { return 1.f / (1.f + expf(-x)); }

// fast sigmoid/tanh on v_exp_f32 + v_rcp_f32 (saturate correctly at +-inf;
// ~1e-6 rel err, far below the int8 quantization noise already present)
__device__ __forceinline__ float sigm_f(float x) {
#ifdef HAS_FASTTRANS
    const float e = __builtin_amdgcn_exp2f(-1.44269504f * x);
    return __builtin_amdgcn_rcpf(1.f + e);
#else
    return 1.f / (1.f + expf(-x));
#endif
}
__device__ __forceinline__ float tanh_f(float x) {
#ifdef HAS_FASTTRANS
    const float e = __builtin_amdgcn_exp2f(-2.88539008f * x);
    return 2.f * __builtin_amdgcn_rcpf(1.f + e) - 1.f;
#else
    return tanhf(x);
#endif
}

__device__ __forceinline__ int dot4i8(unsigned a, unsigned b, int c) {
#ifdef HAS_SDOT4
    return __builtin_amdgcn_sdot4((int)a, (int)b, c, false);
#else
    int s = c;
    #pragma unroll
    for (int i = 0; i < 4; ++i) {
        const int xa = ((int)(a << (24 - 8 * i))) >> 24;
        const int xb = ((int)(b << (24 - 8 * i))) >> 24;
        s += xa * xb;
    }
    return s;
#endif
}

// ---------------------------------------------------------------------------
// prep1: WihP (GEMM B-matrix, j' = u*4+g <-> gate-row g*256+u), bP, WlinQ.
// ---------------------------------------------------------------------------
__global__ void prep1_kernel(const float* __restrict__ Wih_f, const float* __restrict__ b_f,
                             const float* __restrict__ Wih_b, const float* __restrict__ b_b,
                             const float* __restrict__ Wlin,
                             float* __restrict__ WihP, float* __restrict__ bP,
                             float* __restrict__ WlinQ)
{
    int tid = blockIdx.x * blockDim.x + threadIdx.x;   // [0, 2*262144)
    int dir = tid >> 18;
    int r   = tid & 262143;
    int k   = r >> 10;        // 0..255
    int jp  = r & 1023;       // j'
    int u   = jp >> 2;
    int g   = jp & 3;
    int row = g * 256 + u;
    const float* Wih = dir ? Wih_b : Wih_f;
    const float* bv  = dir ? b_b   : b_f;
    WihP[dir * WMAT_PER_DIR + k * 1024 + jp] = Wih[row * 256 + k];
    if (r < 1024) {
        bP[dir * 1024 + jp] = bv[row];
        int uu = r >> 2, tt = r & 3;
        WlinQ[(dir * 256 + uu) * 4 + tt] = Wlin[tt * (2 * Hh) + dir * 256 + uu];
    }
}

// ---------------------------------------------------------------------------
// scale_kernel: per gate-row absmax/127. 512 blocks x 256 thr; wave = one row.
// ---------------------------------------------------------------------------
__global__ __launch_bounds__(256) void scale_kernel(const float* __restrict__ Whh_f,
                                                    const float* __restrict__ Whh_b,
                                                    float* __restrict__ scales)
{
    const int gw = blockIdx.x * 4 + (threadIdx.x >> 6);   // 0..2047
    const int lane = threadIdx.x & 63;
    const int dir = gw >> 10;
    const int row = gw & 1023;
    const float* W = dir ? Whh_b : Whh_f;
    const float* src = W + (size_t)row * 256 + lane * 4;
    float m = fmaxf(fmaxf(fabsf(src[0]), fabsf(src[1])),
                    fmaxf(fabsf(src[2]), fabsf(src[3])));
    #pragma unroll
    for (int off = 32; off > 0; off >>= 1) m = fmaxf(m, __shfl_down(m, off));
    if (lane == 0) scales[gw] = fmaxf(m, 1e-12f) / 127.f;
}

// ---------------------------------------------------------------------------
// quant_kernel: build the permuted int8 image W8 (pair-lane mapping).
// ---------------------------------------------------------------------------
__global__ __launch_bounds__(256) void quant_kernel(const float* __restrict__ Whh_f,
                                                    const float* __restrict__ Whh_b,
                                                    const float* __restrict__ scales,
                                                    unsigned int* __restrict__ W8)
{
    const int idx = blockIdx.x * 256 + threadIdx.x;   // 0..131071
    const int dir = idx >> 16;
    const int rem = idx & 65535;
    int slot, t, j, kw;
    if (rem < STAT_U32) {
        slot = rem >> 11; const int r2 = rem & 2047; t = r2 >> 2; j = r2 & 3;
        kw = 2 * slot + (j >> 1);
    } else {
        const int q2 = rem - STAT_U32;
        slot = q2 >> 11; const int r2 = q2 & 2047; t = r2 >> 2; j = r2 & 3;
        kw = 2 * NSTAT + 2 * slot + (j >> 1);
    }
    const int rr = j & 1;
    const int u  = t >> 1;                 // pair-lane mapping
    const int gs = (t & 1) * 2 + rr;
    const int row = gs * 256 + u;
    const float* W = dir ? Whh_b : Whh_f;
    const float sc = scales[dir * 1024 + row];
    const float inv = 1.f / sc;
    unsigned int v = 0;
    #pragma unroll
    for (int i = 0; i < 4; ++i) {
        const float w = W[(size_t)row * 256 + kw * 4 + i];
        int q = (int)rintf(w * inv);
        q = q > 127 ? 127 : (q < -127 ? -127 : q);
        v |= ((unsigned int)(unsigned char)(signed char)q) << (8 * i);
    }
    W8[idx] = v;
}

// ---------------------------------------------------------------------------
// wl8_kernel: quantize emission weights per (dir, tag). 1 block x 512 thr.
// ---------------------------------------------------------------------------
__global__ __launch_bounds__(512) void wl8_kernel(const float* __restrict__ Wlin,
                                                  unsigned int* __restrict__ wl8T,
                                                  float* __restrict__ scfac)
{
    const int w = threadIdx.x >> 6;      // 0..7
    const int lane = threadIdx.x & 63;
    const int dir = w >> 2, t = w & 3;
    const float4 v = *(const float4*)(Wlin + t * (2 * Hh) + dir * 256 + lane * 4);
    float m = fmaxf(fmaxf(fabsf(v.x), fabsf(v.y)), fmaxf(fabsf(v.z), fabsf(v.w)));
    #pragma unroll
    for (int off = 32; off > 0; off >>= 1) m = fmaxf(m, __shfl_down(m, off));
    const float mall = __builtin_amdgcn_readfirstlane(m);
    const float sc = fmaxf(mall, 1e-12f) / 127.f;
    const float inv = 1.f / sc;
    const float vv[4] = {v.x, v.y, v.z, v.w};
    unsigned int pk = 0;
    #pragma unroll
    for (int i = 0; i < 4; ++i) {
        int q = (int)rintf(vv[i] * inv);
        q = q > 127 ? 127 : (q < -127 ? -127 : q);
        pk |= ((unsigned int)(unsigned char)(signed char)q) << (8 * i);
    }
    wl8T[w * 64 + lane] = pk;
    if (lane == 0) scfac[w] = sc / 127.f;
}

// ---------------------------------------------------------------------------
// embproj GEMM: embproj[dir][v][j'] = sum_e emb[v][e]*WihP[dir][e][j'] + bP[dir][j']
// ---------------------------------------------------------------------------
#define BM 64
#define BN 128
#define BK 16
__global__ __launch_bounds__(256) void embproj_gemm(const float* __restrict__ emb,
                                                    const float* __restrict__ WihP,
                                                    const float* __restrict__ bP,
                                                    float* __restrict__ embproj)
{
    int dir = blockIdx.z;
    const float* Bmat = WihP + dir * WMAT_PER_DIR;
    float* C = embproj + (size_t)dir * EPROJ_PER_DIR;
    int m0 = blockIdx.x * BM;
    int n0 = blockIdx.y * BN;

    __shared__ float As[BK][BM];
    __shared__ float Bs[BK][BN];

    int t = threadIdx.x;
    int tm = (t & 15) * 4;
    int tn = (t >> 4) * 8;
    float acc[4][8];
    #pragma unroll
    for (int i = 0; i < 4; ++i)
        #pragma unroll
        for (int j = 0; j < 8; ++j) acc[i][j] = 0.f;

    for (int k0 = 0; k0 < Ee; k0 += BK) {
        {   // A tile 64x16
            int row = t >> 2, seg = t & 3;
            float4 a4 = *(const float4*)(&emb[(size_t)(m0 + row) * Ee + k0 + seg * 4]);
            As[seg * 4 + 0][row] = a4.x;
            As[seg * 4 + 1][row] = a4.y;
            As[seg * 4 + 2][row] = a4.z;
            As[seg * 4 + 3][row] = a4.w;
        }
        {   // B tile 16x128
            int kk = t >> 4, nn = (t & 15) * 8;
            float4 b0 = *(const float4*)(&Bmat[(size_t)(k0 + kk) * 1024 + n0 + nn]);
            float4 b1 = *(const float4*)(&Bmat[(size_t)(k0 + kk) * 1024 + n0 + nn + 4]);
            *(float4*)&Bs[kk][nn]     = b0;
            *(float4*)&Bs[kk][nn + 4] = b1;
        }
        __syncthreads();
        #pragma unroll
        for (int k = 0; k < BK; ++k) {
            float4 a  = *(const float4*)&As[k][tm];
            float4 b0 = *(const float4*)&Bs[k][tn];
            float4 b1 = *(const float4*)&Bs[k][tn + 4];
            float av[4] = {a.x, a.y, a.z, a.w};
            float bv[8] = {b0.x, b0.y, b0.z, b0.w, b1.x, b1.y, b1.z, b1.w};
            #pragma unroll
            for (int i = 0; i < 4; ++i)
                #pragma unroll
                for (int j = 0; j < 8; ++j)
                    acc[i][j] += av[i] * bv[j];
        }
        __syncthreads();
    }
    #pragma unroll
    for (int i = 0; i < 4; ++i) {
        int m = m0 + tm + i;
        #pragma unroll
        for (int j = 0; j < 8; j += 4) {
            float4 o;
            o.x = acc[i][j + 0] + bP[dir * 1024 + n0 + tn + j + 0];
            o.y = acc[i][j + 1] + bP[dir * 1024 + n0 + tn + j + 1];
            o.z = acc[i][j + 2] + bP[dir * 1024 + n0 + tn + j + 2];
            o.w = acc[i][j + 3] + bP[dir * 1024 + n0 + tn + j + 3];
            *(float4*)&C[(size_t)m * 1024 + n0 + tn + j] = o;
        }
    }
}

// ---------------------------------------------------------------------------
// R19 = R17 verbatim (best measured: lstm 653us, total 903us). R18's k-split
// (16 waves, 4/SIMD) regressed to 910us: the extra barrier + int2 LDS partial
// exchange + per-wave overhead outweighed the latency hiding. R17 is the
// measured optimum of this structure:
//  - sync-free, one WG per (dir,batch), int8 sdot4, weights LDS+L2,
//  - fast transcendentals on the h-critical path,
//  - 4 accumulator chains per gate output,
//  - emission spread over waves 4-7, ep software-pipelined, 1 barrier/step.
// ---------------------------------------------------------------------------
__global__ __attribute__((amdgpu_flat_work_group_size(512, 512)))
__attribute__((amdgpu_waves_per_eu(2, 2))) void lstm_stream_kernel(
    const int* __restrict__ sentence,
    const float* __restrict__ embproj,
    const unsigned int* __restrict__ W8,
    const float* __restrict__ scales,
    const unsigned int* __restrict__ wl8T,
    const float* __restrict__ scfac,
    float* __restrict__ emisP)
{
    extern __shared__ char smem[];
    uint4*        SWl = (uint4*)smem;                       // NSTAT*512 uint4 = 64KB
    unsigned int* h8  = (unsigned int*)(smem + STAT_U32*4); // [2][64] u32

    const int bx  = blockIdx.x;
    const int dir = bx >> 6;
    const int b   = bx & 63;
    const int t   = threadIdx.x;
    const int lane = t & 63, wv = t >> 6;
    const int u    = t >> 1;            // pair-lane unit
    const int gs0  = (t & 1) * 2;       // 0: rows i,f | 2: rows g,o
    const bool ev  = !(t & 1);

    const unsigned int* Wd   = W8 + (size_t)dir * 65536;
    const unsigned int* Wstr = Wd + STAT_U32;

    // stage static weight section into LDS (coalesced)
    #pragma unroll
    for (int i = 0; i < NSTAT; ++i)
        SWl[i * 512 + t] = *(const uint4*)(Wd + (size_t)(i * 512 + t) * 4);
    if (t < 128) h8[t] = 0u;   // h(-1) = 0, both parity slots

    const float sc0 = scales[dir * 1024 + (gs0 + 0) * 256 + u] * (1.f / 127.f);
    const float sc1 = scales[dir * 1024 + (gs0 + 1) * 256 + u] * (1.f / 127.f);
    const float* EP = embproj + (size_t)dir * EPROJ_PER_DIR;
    const int* sent = sentence + (size_t)b * Ss;
    float c = 0.f;

    // emission state: waves 4..7, one tag each
    unsigned int wlq = 0;
    float efac = 0.f;
    const int etag = wv - 4;
    if (wv >= 4) {
        wlq  = wl8T[(dir * 4 + etag) * 64 + lane];
        efac = scfac[dir * 4 + etag];
    }

    // ep software pipeline: preload step 0
    float2 ep_cur;
    {
        const int pos0 = dir ? (Ss - 1) : 0;
        ep_cur = *(const float2*)(EP + (size_t)sent[pos0] * 1024 + u * 4 + gs0);
    }

    __syncthreads();

    for (int s = 0; s < Ss; ++s) {
        // issue next step's ep load early
        float2 ep_nxt = make_float2(0.f, 0.f);
        if (s + 1 < Ss) {
            const int pn = dir ? (Ss - 2 - s) : (s + 1);
            ep_nxt = *(const float2*)(EP + (size_t)sent[pn] * 1024 + u * 4 + gs0);
        }

        const int rp = (s + 1) & 1;        // slot holding h(s-1)
        const int wp = s & 1;              // slot to write h(s)
        const int v_h = (int)h8[rp * 64 + lane];

        // streamed weight slots (L2-resident; compiler re-loads per step)
        uint4 sb[NSTRM];
        #pragma unroll
        for (int i = 0; i < NSTRM; ++i)
            sb[i] = *(const uint4*)(Wstr + (size_t)(i * 512 + t) * 4);

        // emission of h(s-1): waves 4-7, one tag each (1 sdot4 + reduce)
        if (wv >= 4 && s > 0) {
            int e = dot4i8(wlq, (unsigned)v_h, 0);
            #pragma unroll
            for (int off = 32; off > 0; off >>= 1) e += __shfl_down(e, off);
            if (lane == 0) {
                const int pp = dir ? (Ss - s) : (s - 1);
                emisP[(((size_t)dir * Ss + pp) * Bb + b) * 4 + etag] = (float)e * efac;
            }
        }

        // gate dots: readlane h (uniform SGPR) x int8 weights; 4 chains/output
        int a0c[4] = {0, 0, 0, 0};
        int a1c[4] = {0, 0, 0, 0};
        #pragma unroll
        for (int i = 0; i < NSTAT; ++i) {
            const uint4 w = SWl[i * 512 + t];
            const unsigned h0 = (unsigned)__builtin_amdgcn_readlane(v_h, 2 * i);
            const unsigned h1 = (unsigned)__builtin_amdgcn_readlane(v_h, 2 * i + 1);
            const int q = i & 3;
            a0c[q] = dot4i8(w.x, h0, a0c[q]); a1c[q] = dot4i8(w.y, h0, a1c[q]);
            a0c[q] = dot4i8(w.z, h1, a0c[q]); a1c[q] = dot4i8(w.w, h1, a1c[q]);
        }
        #pragma unroll
        for (int i = 0; i < NSTRM; ++i) {
            const uint4 w = sb[i];
            const unsigned h0 = (unsigned)__builtin_amdgcn_readlane(v_h, 2 * NSTAT + 2 * i);
            const unsigned h1 = (unsigned)__builtin_amdgcn_readlane(v_h, 2 * NSTAT + 2 * i + 1);
            const int q = i & 3;
            a0c[q] = dot4i8(w.x, h0, a0c[q]); a1c[q] = dot4i8(w.y, h0, a1c[q]);
            a0c[q] = dot4i8(w.z, h1, a0c[q]); a1c[q] = dot4i8(w.w, h1, a1c[q]);
        }
        const int a0 = (a0c[0] + a0c[1]) + (a0c[2] + a0c[3]);
        const int a1 = (a1c[0] + a1c[1]) + (a1c[2] + a1c[3]);

        const float g0 = (float)a0 * sc0 + ep_cur.x;   // ev: i  | odd: g
        const float g1 = (float)a1 * sc1 + ep_cur.y;   // ev: f  | odd: o
        // pair exchange: even lane gets (g,o) from odd partner
        const float pg0 = __shfl_xor(g0, 1);
        const float pg1 = __shfl_xor(g1, 1);
        if (ev) {
            c = sigm_f(g1) * c + sigm_f(g0) * tanh_f(pg0);
            const float h = sigm_f(pg1) * tanh_f(c);
            ((char*)h8)[wp * 256 + u] = (char)(int)rintf(h * 127.f);   // |h|<1
        }
        ep_cur = ep_nxt;
        __syncthreads();   // separates step-s h8 reads from step-s+1 writes
    }

    // epilogue: emission for h(Ss-1)
    if (wv >= 4) {
        const int v_h = (int)h8[((Ss - 1) & 1) * 64 + lane];
        int e = dot4i8(wlq, (unsigned)v_h, 0);
        #pragma unroll
        for (int off = 32; off > 0; off >>= 1) e += __shfl_down(e, off);
        if (lane == 0) {
            const int pp = dir ? 0 : (Ss - 1);
            emisP[(((size_t)dir * Ss + pp) * Bb + b) * 4 + etag] = (float)e * efac;
        }
    }
}

// ---------------------------------------------------------------------------
// Fused CRF + Viterbi tail. grid 8 x 64 threads. emis = emisP[0] + emisP[1].
// ---------------------------------------------------------------------------
#define EM2(S_, B_, J_) (emisA[(((size_t)(S_)) * Bb + (B_)) * 4 + (J_)] + \
                         emisB[(((size_t)(S_)) * Bb + (B_)) * 4 + (J_)])

__global__ __launch_bounds__(64) void tail_kernel(
    const float* __restrict__ emisA, const float* __restrict__ emisB,
    const float* __restrict__ blin, const float* __restrict__ start_t,
    const float* __restrict__ end_t, const float* __restrict__ trans,
    const int* __restrict__ tags, float* __restrict__ out_tags,
    float* __restrict__ out_loss)
{
    const int blk = blockIdx.x;
    const int t = threadIdx.x;
    const int b_loc = t >> 2, j = t & 3;
    const int base = t & ~3;

    if (blk < 4) {
        __shared__ unsigned char bp_sh[16][513][4];
        __shared__ unsigned char tag_sh[16][520];
        const int b = blk * 16 + b_loc;
        const float trj0 = trans[0*4+j], trj1 = trans[1*4+j],
                    trj2 = trans[2*4+j], trj3 = trans[3*4+j];
        const float blj = blin[j];
        float score = start_t[j] + EM2(0, b, j) + blj;
        for (int s = 1; s < Ss; ++s) {
            const float e = EM2(s, b, j) + blj;
            const float s0 = __shfl(score, base+0), s1 = __shfl(score, base+1),
                        s2 = __shfl(score, base+2), s3 = __shfl(score, base+3);
            float best = s0 + trj0; int bi = 0;
            float v = s1 + trj1; if (v > best) { best = v; bi = 1; }
            v = s2 + trj2; if (v > best) { best = v; bi = 2; }
            v = s3 + trj3; if (v > best) { best = v; bi = 3; }
            score = best + e;
            bp_sh[b_loc][s][j] = (unsigned char)bi;
        }
        const float fv = score + end_t[j];
        const float f0 = __shfl(fv, base+0), f1 = __shfl(fv, base+1),
                    f2 = __shfl(fv, base+2), f3 = __shfl(fv, base+3);
        __syncthreads();
        if (j == 0) {   // backtrack (first-occurrence argmax, like jnp)
            float best = f0; int tag = 0;
            if (f1 > best) { best = f1; tag = 1; }
            if (f2 > best) { best = f2; tag = 2; }
            if (f3 > best) { best = f3; tag = 3; }
            tag_sh[b_loc][Ss-1] = (unsigned char)tag;
            for (int s = Ss - 1; s >= 1; --s) {
                tag = bp_sh[b_loc][s][tag];
                tag_sh[b_loc][s-1] = (unsigned char)tag;
            }
        }
        __syncthreads();
        for (int idx = t; idx < 16 * Ss; idx += 64) {
            const int bl = idx >> 9, s = idx & (Ss - 1);
            out_tags[(size_t)(blk*16 + bl) * Ss + s] = (float)tag_sh[bl][s];
        }
    } else {
        const int b = (blk - 4) * 16 + b_loc;
        const float trj0 = trans[0*4+j], trj1 = trans[1*4+j],
                    trj2 = trans[2*4+j], trj3 = trans[3*4+j];
        const float blj = blin[j];
        float alpha = start_t[j] + EM2(0, b, j) + blj;
        for (int s = 1; s < Ss; ++s) {
            const float e = EM2(s, b, j) + blj;
            const float a0 = __shfl(alpha, base+0), a1 = __shfl(alpha, base+1),
                        a2 = __shfl(alpha, base+2), a3 = __shfl(alpha, base+3);
            const float x0 = a0 + trj0, x1 = a1 + trj1, x2 = a2 + trj2, x3 = a3 + trj3;
            const float m = fmaxf(fmaxf(x0, x1), fmaxf(x2, x3));
            alpha = m + logf(expf(x0-m) + expf(x1-m) + expf(x2-m) + expf(x3-m)) + e;
        }
        const float dv = alpha + end_t[j];
        const float d0 = __shfl(dv, base+0), d1 = __shfl(dv, base+1),
                    d2 = __shfl(dv, base+2), d3 = __shfl(dv, base+3);
        const float dm = fmaxf(fmaxf(d0, d1), fmaxf(d2, d3));
        const float denom = dm + logf(expf(d0-dm) + expf(d1-dm) + expf(d2-dm) + expf(d3-dm));

        const int lo = j * 128, hi = lo + 128;
        float num = 0.f;
        int tprev = (lo > 0) ? tags[(size_t)b*Ss + lo - 1] : 0;
        if (j == 0) num += start_t[tags[(size_t)b*Ss]];
        if (j == 3) num += end_t[tags[(size_t)b*Ss + Ss - 1]];
        for (int s = lo; s < hi; ++s) {
            const int tg = tags[(size_t)b*Ss + s];
            num += EM2(s, b, tg) + blin[tg];
            if (s > 0) num += trans[tprev*4 + tg];
            tprev = tg;
        }
        num += __shfl_xor(num, 1);
        num += __shfl_xor(num, 2);
        float lb = (j == 0) ? (denom - num) : 0.f;
        #pragma unroll
        for (int off = 32; off > 0; off >>= 1) lb += __shfl_down(lb, off);
        if (t == 0) atomicAdd(out_loss, lb);
    }
}

// ---------------------------------------------------------------------------
extern "C" void kernel_launch(void* const* d_in, const int* in_sizes, int n_in,
                              void* d_out, int out_size, void* d_ws, size_t ws_size,
                              hipStream_t stream)
{
    const int*   sentence = (const int*)d_in[0];
    const int*   tags     = (const int*)d_in[1];
    const float* emb      = (const float*)d_in[3];
    const float* Wih_f    = (const float*)d_in[4];
    const float* Whh_f    = (const float*)d_in[5];
    const float* b_f      = (const float*)d_in[6];
    const float* Wih_b    = (const float*)d_in[7];
    const float* Whh_b    = (const float*)d_in[8];
    const float* b_b      = (const float*)d_in[9];
    const float* Wlin     = (const float*)d_in[10];
    const float* blin     = (const float*)d_in[11];
    const float* start_t  = (const float*)d_in[12];
    const float* end_t    = (const float*)d_in[13];
    const float* trans    = (const float*)d_in[14];

    // workspace layout (floats)
    float*        embproj = (float*)d_ws;                      // 16,384,000
    float*        WihP    = embproj + 2 * EPROJ_PER_DIR;       // 524,288
    float*        bP      = WihP + 2 * WMAT_PER_DIR;           // 2048
    float*        WlinQ   = bP + 2048;                         // 2048
    float*        scales  = WlinQ + 2048;                      // 2048
    unsigned int* W8      = (unsigned int*)(scales + 2048);    // 131,072 u32
    unsigned int* wl8T    = W8 + 131072;                       // 512 u32
    float*        scfac   = (float*)(wl8T + 512);              // 8
    float*        emisP   = scfac + 56;                        // 2*512*64*4 (16B aligned)
    float*        emisA   = emisP;
    float*        emisB   = emisP + Ss * Bb * 4;

    prep1_kernel<<<2048, 256, 0, stream>>>(Wih_f, b_f, Wih_b, b_b, Wlin,
                                           WihP, bP, WlinQ);
    scale_kernel<<<512, 256, 0, stream>>>(Whh_f, Whh_b, scales);
    quant_kernel<<<512, 256, 0, stream>>>(Whh_f, Whh_b, scales, W8);
    wl8_kernel<<<1, 512, 0, stream>>>(Wlin, wl8T, scfac);

    dim3 gg(Vv / BM, 1024 / BN, 2);
    embproj_gemm<<<gg, 256, 0, stream>>>(emb, WihP, bP, embproj);

    lstm_stream_kernel<<<128, 512, STAT_U32 * 4 + 512, stream>>>(
        sentence, embproj, W8, scales, wl8T, scfac, emisP);

    float* out = (float*)d_out;
    float* out_loss = out + Bb * Ss;
    hipMemsetAsync(out_loss, 0, sizeof(float), stream);
    tail_kernel<<<8, 64, 0, stream>>>(emisA, emisB, blin, start_t, end_t, trans,
                                      tags, out, out_loss);
}